// Round 1
// baseline (741.451 us; speedup 1.0000x reference)
//
#include <hip/hip_runtime.h>

typedef __bf16 bf16;
typedef __attribute__((ext_vector_type(8))) __bf16 bf16x8;
typedef __attribute__((ext_vector_type(4))) float f32x4;

#define AS1 __attribute__((address_space(1)))
#define AS3 __attribute__((address_space(3)))

// tuple tables: combinations(range(8), 2), lexicographic
__device__ __constant__ int c_T0[28] = {0,0,0,0,0,0,0,1,1,1,1,1,1,2,2,2,2,2,3,3,3,3,4,4,4,5,5,6};
__device__ __constant__ int c_T1[28] = {1,2,3,4,5,6,7,2,3,4,5,6,7,3,4,5,6,7,4,5,6,7,5,6,7,6,7,7};

// ---------------------------------------------------------------------------
// X = [frames 4224 x 2048] bf16, frame f: queries f<4000, support 4000..4199,
// pad rows >=4200 zero.  Adds positional encoding PE[s][d].
__global__ __launch_bounds__(256) void fill_x(
    const float* __restrict__ queries, const float* __restrict__ support,
    bf16* __restrict__ X)
{
    const int f = blockIdx.x, tid = threadIdx.x;
    bf16* row = X + (long)f * 2048;
    const int d0 = tid << 3;
    if (f >= 4200) {
        bf16x8 z;
        #pragma unroll
        for (int i = 0; i < 8; ++i) z[i] = (bf16)0.f;
        *(bf16x8*)(row + d0) = z;
        return;
    }
    const float* src = (f < 4000) ? (queries + (long)f * 2048)
                                  : (support + (long)(f - 4000) * 2048);
    const int s = f & 7;
    bf16x8 o;
    #pragma unroll
    for (int i = 0; i < 8; ++i) {
        int d = d0 + i;
        float dv = __expf((float)(d >> 1) * -0.008994473019508f); // -ln(1e4)/1024
        float ang = (float)s * dv;
        float pe = (d & 1) ? __cosf(ang) : __sinf(ang);
        o[i] = (bf16)(src[d] + pe);
    }
    *(bf16x8*)(row + d0) = o;
}

// ---------------------------------------------------------------------------
// Wp [4608][2048] bf16 = transposed halves: n<1152: k_w[0:2048], 1152..: k_w[2048:],
// 2304..: v_w[0:2048], 3456..: v_w[2048:]
__global__ __launch_bounds__(256) void pack_w(
    const float* __restrict__ kw, const float* __restrict__ vw, bf16* __restrict__ Wp)
{
    __shared__ float t[32][33];
    const int k0 = blockIdx.x << 5, n0g = blockIdx.y << 5;
    const int tx = threadIdx.x & 31, ty = threadIdx.x >> 5;
    const int j = n0g / 1152, nc = n0g % 1152;
    const float* src = ((j < 2) ? kw : vw) + (long)(((j & 1) << 11) + k0) * 1152 + nc;
    #pragma unroll
    for (int i = 0; i < 4; ++i)
        t[ty + (i << 3)][tx] = src[(long)(ty + (i << 3)) * 1152 + tx];
    __syncthreads();
    #pragma unroll
    for (int i = 0; i < 4; ++i)
        Wp[(long)(n0g + ty + (i << 3)) * 2048 + k0 + tx] = (bf16)t[tx][ty + (i << 3)];
}

// ---------------------------------------------------------------------------
// C[M,N] (f32) = scale * A[M,K](bf16,row-major) x B[N,K](bf16,row-major)^T
// M,N multiples of 128; K multiple of 32.  m97-style: 128x128 tile, 4 waves 2x2,
// global_load_lds width=16, 16x16x32 bf16 MFMA.
__global__ __launch_bounds__(256) void gemm_bt(
    const bf16* __restrict__ A, const bf16* __restrict__ B, float* __restrict__ C,
    int N, int K, float scale, int tiles_n)
{
    __shared__ __align__(16) bf16 lA[128 * 32];
    __shared__ __align__(16) bf16 lB[128 * 32];
    const int tid = threadIdx.x;
    const int wid = tid >> 6, lane = tid & 63;
    const int wm = (wid >> 1) << 6, wn = (wid & 1) << 6;
    const int quad = lane >> 4, l16 = lane & 15;
    const int tm = blockIdx.x / tiles_n, tn = blockIdx.x % tiles_n;
    const int m0 = tm << 7, n0 = tn << 7;

    f32x4 acc[4][4];
    #pragma unroll
    for (int i = 0; i < 4; ++i)
        #pragma unroll
        for (int j = 0; j < 4; ++j)
            #pragma unroll
            for (int r = 0; r < 4; ++r) acc[i][j][r] = 0.f;

    const int srow = lane >> 2, scol = (lane & 3) << 3;
    for (int kk = 0; kk < K; kk += 32) {
        __syncthreads();
        #pragma unroll
        for (int p = 0; p < 2; ++p) {
            const int rbase = (wid << 5) + (p << 4);
            const bf16* ga = A + (long)(m0 + rbase + srow) * K + kk + scol;
            const bf16* gb = B + (long)(n0 + rbase + srow) * K + kk + scol;
            __builtin_amdgcn_global_load_lds((const AS1 unsigned int*)ga,
                                             (AS3 unsigned int*)(lA + rbase * 32), 16, 0, 0);
            __builtin_amdgcn_global_load_lds((const AS1 unsigned int*)gb,
                                             (AS3 unsigned int*)(lB + rbase * 32), 16, 0, 0);
        }
        __builtin_amdgcn_s_waitcnt(0);
        __syncthreads();
        bf16x8 af[4], bfr[4];
        #pragma unroll
        for (int i = 0; i < 4; ++i)
            af[i] = *(const bf16x8*)(lA + (wm + (i << 4) + l16) * 32 + (quad << 3));
        #pragma unroll
        for (int j = 0; j < 4; ++j)
            bfr[j] = *(const bf16x8*)(lB + (wn + (j << 4) + l16) * 32 + (quad << 3));
        #pragma unroll
        for (int i = 0; i < 4; ++i)
            #pragma unroll
            for (int j = 0; j < 4; ++j)
                acc[i][j] = __builtin_amdgcn_mfma_f32_16x16x32_bf16(af[i], bfr[j], acc[i][j], 0, 0, 0);
    }
    #pragma unroll
    for (int i = 0; i < 4; ++i) {
        const int row = m0 + wm + (i << 4) + (quad << 2);
        #pragma unroll
        for (int j = 0; j < 4; ++j) {
            const int col = n0 + wn + (j << 4) + l16;
            float* cp = C + (long)row * N + col;
            #pragma unroll
            for (int r = 0; r < 4; ++r) cp[(long)r * N] = acc[i][j][r] * scale;
        }
    }
}

// ---------------------------------------------------------------------------
// One block per tuple-row: assemble K/V projections from half-projections H,
// LayerNorm on K, store bf16.  Pad rows -> zeros.
// H[f][0:1152]=k_top, [1152:2304]=k_bot, [2304:3456]=v_top, [3456:4608]=v_bot.
__global__ __launch_bounds__(256) void proj_rows(
    const float* __restrict__ H, const float* __restrict__ kb,
    const float* __restrict__ vb, const float* __restrict__ gamma,
    const float* __restrict__ beta,
    bf16* __restrict__ qks, bf16* __restrict__ qvs,
    bf16* __restrict__ sks, bf16* __restrict__ svs)
{
    const int bid = blockIdx.x, tid = threadIdx.x;
    bf16 *outK, *outV;
    int fi = 0, fj = 0;
    bool valid;
    if (bid < 14080) {
        outK = qks + (long)bid * 1152;
        outV = qvs + (long)bid * 1152;
        valid = (bid < 14000);
        if (valid) {
            int q = bid / 28, t = bid - q * 28;
            fi = (q << 3) + c_T0[t];
            fj = (q << 3) + c_T1[t];
        }
    } else {
        int m2 = bid - 14080;
        outK = sks + (long)m2 * 1152;
        outV = svs + (long)m2 * 1152;
        valid = (m2 < 700);
        if (valid) {
            int n = m2 / 28, t = m2 - n * 28;
            fi = 4000 + (n << 3) + c_T0[t];
            fj = 4000 + (n << 3) + c_T1[t];
        }
    }
    if (!valid) {
        for (int d = tid; d < 1152; d += 256) { outK[d] = (bf16)0.f; outV[d] = (bf16)0.f; }
        return;
    }
    const float* Hi = H + (long)fi * 4608;
    const float* Hj = H + (long)fj * 4608;
    float xv[5];
    float sum = 0.f, sumsq = 0.f;
    #pragma unroll
    for (int it = 0; it < 5; ++it) {
        int d = tid + (it << 8);
        float x = 0.f;
        if (d < 1152) {
            x = Hi[d] + Hj[1152 + d] + kb[d];
            sum += x; sumsq += x * x;
        }
        xv[it] = x;
    }
    #pragma unroll
    for (int off = 32; off > 0; off >>= 1) {
        sum += __shfl_xor(sum, off, 64);
        sumsq += __shfl_xor(sumsq, off, 64);
    }
    __shared__ float s1[4], s2[4];
    const int wid = tid >> 6;
    if ((tid & 63) == 0) { s1[wid] = sum; s2[wid] = sumsq; }
    __syncthreads();
    sum = s1[0] + s1[1] + s1[2] + s1[3];
    sumsq = s2[0] + s2[1] + s2[2] + s2[3];
    const float mu = sum * (1.f / 1152.f);
    const float var = sumsq * (1.f / 1152.f) - mu * mu;
    const float rs = rsqrtf(var + 1e-5f);
    #pragma unroll
    for (int it = 0; it < 5; ++it) {
        int d = tid + (it << 8);
        if (d < 1152) outK[d] = (bf16)((xv[it] - mu) * rs * gamma[d] + beta[d]);
    }
    #pragma unroll
    for (int it = 0; it < 5; ++it) {
        int d = tid + (it << 8);
        if (d < 1152) outV[d] = (bf16)(Hi[2304 + d] + Hj[3456 + d] + vb[d]);
    }
}

// ---------------------------------------------------------------------------
// svs [768][1152] -> svsT [1152][768]
__global__ __launch_bounds__(256) void transpose_svs(
    const bf16* __restrict__ svs, bf16* __restrict__ svsT)
{
    __shared__ float t[32][33];
    const int r0 = blockIdx.x << 5, c0 = blockIdx.y << 5;
    const int tx = threadIdx.x & 31, ty = threadIdx.x >> 5;
    #pragma unroll
    for (int i = 0; i < 4; ++i)
        t[ty + (i << 3)][tx] = (float)svs[(long)(r0 + ty + (i << 3)) * 1152 + c0 + tx];
    __syncthreads();
    #pragma unroll
    for (int i = 0; i < 4; ++i)
        svsT[(long)(c0 + ty + (i << 3)) * 768 + r0 + tx] = (bf16)t[tx][ty + (i << 3)];
}

// ---------------------------------------------------------------------------
// Per query-tuple row: 5 independent softmaxes over 140 (one wave each).
__global__ __launch_bounds__(320) void softmax_attn(
    const float* __restrict__ scores, bf16* __restrict__ attn)
{
    const int m = blockIdx.x, tid = threadIdx.x;
    bf16* arow = attn + (long)m * 768;
    if (m >= 14000) {
        for (int d = tid; d < 768; d += 320) arow[d] = (bf16)0.f;
        return;
    }
    const int w = tid >> 6, lane = tid & 63;
    const float* srow = scores + (long)m * 768 + w * 140;
    float v0 = srow[lane];
    float v1 = srow[64 + lane];
    float v2 = (lane < 12) ? srow[128 + lane] : -1e30f;
    float mx = fmaxf(fmaxf(v0, v1), v2);
    #pragma unroll
    for (int off = 32; off > 0; off >>= 1) mx = fmaxf(mx, __shfl_xor(mx, off, 64));
    float e0 = __expf(v0 - mx), e1 = __expf(v1 - mx);
    float e2 = (lane < 12) ? __expf(v2 - mx) : 0.f;
    float s = e0 + e1 + e2;
    #pragma unroll
    for (int off = 32; off > 0; off >>= 1) s += __shfl_xor(s, off, 64);
    const float inv = 1.f / s;
    bf16* aw = arow + w * 140;
    aw[lane] = (bf16)(e0 * inv);
    aw[64 + lane] = (bf16)(e1 * inv);
    if (lane < 12) aw[128 + lane] = (bf16)(e2 * inv);
}

// ---------------------------------------------------------------------------
// Fused proto GEMM (per class, K=140) + squared-diff vs q_vs + dist reduction.
// Block: 128 rows x 128 cols of the [14080 x 1152] space; loops 5 classes.
__global__ __launch_bounds__(256) void proto_dist(
    const bf16* __restrict__ attn, const bf16* __restrict__ svsT,
    const bf16* __restrict__ qvs, float* __restrict__ dist)
{
    __shared__ __align__(16) bf16 lA[128 * 32];
    __shared__ __align__(16) bf16 lB[128 * 32];
    __shared__ __align__(16) bf16 lQ[128 * 128];
    __shared__ float rowsum[128];
    const int tid = threadIdx.x;
    const int wid = tid >> 6, lane = tid & 63;
    const int wm = (wid >> 1) << 6, wn = (wid & 1) << 6;
    const int quad = lane >> 4, l16 = lane & 15;
    const int tm = blockIdx.x / 9, tn = blockIdx.x % 9;
    const int m0 = tm << 7, n0 = tn << 7;

    #pragma unroll
    for (int it = 0; it < 8; ++it) {
        int idx = it * 256 + tid;
        int r = idx >> 4, c = (idx & 15) << 3;
        *(bf16x8*)(lQ + r * 128 + c) = *(const bf16x8*)(qvs + (long)(m0 + r) * 1152 + n0 + c);
    }

    const int sr = tid >> 1, sh = (tid & 1) << 4;
    for (int cls = 0; cls < 5; ++cls) {
        const int cb = cls * 140;
        f32x4 acc[4][4];
        #pragma unroll
        for (int i = 0; i < 4; ++i)
            #pragma unroll
            for (int j = 0; j < 4; ++j)
                #pragma unroll
                for (int r = 0; r < 4; ++r) acc[i][j][r] = 0.f;

        for (int kc = 0; kc < 140; kc += 32) {
            __syncthreads();
            { // A tile: attn[m0+sr][cb+kc+sh .. +15], zero-pad k>=140
                const bf16* src = attn + (long)(m0 + sr) * 768 + cb + kc + sh;
                bf16* dst = lA + sr * 32 + sh;
                if (kc + sh + 15 < 140) {
                    *(bf16x8*)dst = *(const bf16x8*)src;
                    *(bf16x8*)(dst + 8) = *(const bf16x8*)(src + 8);
                } else {
                    #pragma unroll
                    for (int i = 0; i < 16; ++i)
                        dst[i] = (kc + sh + i < 140) ? src[i] : (bf16)0.f;
                }
            }
            { // B tile: svsT[n0+sr][cb+kc+sh .. +15]
                const bf16* src = svsT + (long)(n0 + sr) * 768 + cb + kc + sh;
                bf16* dst = lB + sr * 32 + sh;
                if (kc + sh + 15 < 140) {
                    *(bf16x8*)dst = *(const bf16x8*)src;
                    *(bf16x8*)(dst + 8) = *(const bf16x8*)(src + 8);
                } else {
                    #pragma unroll
                    for (int i = 0; i < 16; ++i)
                        dst[i] = (kc + sh + i < 140) ? src[i] : (bf16)0.f;
                }
            }
            __syncthreads();
            bf16x8 af[4], bfr[4];
            #pragma unroll
            for (int i = 0; i < 4; ++i)
                af[i] = *(const bf16x8*)(lA + (wm + (i << 4) + l16) * 32 + (quad << 3));
            #pragma unroll
            for (int j = 0; j < 4; ++j)
                bfr[j] = *(const bf16x8*)(lB + (wn + (j << 4) + l16) * 32 + (quad << 3));
            #pragma unroll
            for (int i = 0; i < 4; ++i)
                #pragma unroll
                for (int j = 0; j < 4; ++j)
                    acc[i][j] = __builtin_amdgcn_mfma_f32_16x16x32_bf16(af[i], bfr[j], acc[i][j], 0, 0, 0);
        }
        __syncthreads();
        if (tid < 128) rowsum[tid] = 0.f;
        __syncthreads();
        #pragma unroll
        for (int i = 0; i < 4; ++i) {
            #pragma unroll
            for (int r = 0; r < 4; ++r) {
                const int row = wm + (i << 4) + (quad << 2) + r;
                float s = 0.f;
                #pragma unroll
                for (int j = 0; j < 4; ++j) {
                    const int col = wn + (j << 4) + l16;
                    float qv = (float)lQ[row * 128 + col];
                    float d = qv - acc[i][j][r];
                    s += d * d;
                }
                #pragma unroll
                for (int off = 1; off < 16; off <<= 1) s += __shfl_xor(s, off, 64);
                if (l16 == 0) atomicAdd(&rowsum[row], s);
            }
        }
        __syncthreads();
        if (tid < 128) {
            int m = m0 + tid;
            if (m < 14000) atomicAdd(&dist[cls * 500 + m / 28], rowsum[tid]);
        }
    }
}

// ---------------------------------------------------------------------------
__global__ void finalize(const float* __restrict__ dist, const float* __restrict__ gt,
                         const float* __restrict__ tw, float* __restrict__ out)
{
    int i = blockIdx.x * 256 + threadIdx.x;
    if (i < 2500) {
        int q = i / 5, c = i - q * 5;
        out[i] = -dist[c * 500 + q] * (gt[0] * tw[0] * (1.f / 28.f));
    }
}

// ---------------------------------------------------------------------------
extern "C" void kernel_launch(void* const* d_in, const int* in_sizes, int n_in,
                              void* d_out, int out_size, void* d_ws, size_t ws_size,
                              hipStream_t stream)
{
    const float* support = (const float*)d_in[0];
    const float* queries = (const float*)d_in[2];
    const float* kw      = (const float*)d_in[3];
    const float* kb      = (const float*)d_in[4];
    const float* vw      = (const float*)d_in[5];
    const float* vb      = (const float*)d_in[6];
    const float* gamma   = (const float*)d_in[7];
    const float* beta    = (const float*)d_in[8];
    const float* gt      = (const float*)d_in[9];
    const float* tw      = (const float*)d_in[10];
    float* out = (float*)d_out;

    char* ws = (char*)d_ws;
    size_t off = 0;
    auto alloc = [&](size_t b) { char* p = ws + off; off += (b + 255) & ~(size_t)255; return p; };
    bf16* X    = (bf16*)alloc(4224ull * 2048 * 2);
    bf16* Wp   = (bf16*)alloc(4608ull * 2048 * 2);
    bf16* qks  = (bf16*)alloc(14080ull * 1152 * 2);
    bf16* qvs  = (bf16*)alloc(14080ull * 1152 * 2);
    bf16* sks  = (bf16*)alloc(768ull * 1152 * 2);
    bf16* svs  = (bf16*)alloc(768ull * 1152 * 2);
    bf16* svsT = (bf16*)alloc(1152ull * 768 * 2);
    bf16* attn = (bf16*)alloc(14080ull * 768 * 2);
    float* dist = (float*)alloc(5 * 500 * 4);
    float* H   = (float*)alloc(4224ull * 4608 * 4);
    float* scores = H; // H dead once proj_rows completes; alias

    hipMemsetAsync(dist, 0, 5 * 500 * 4, stream);
    fill_x<<<4224, 256, 0, stream>>>(queries, support, X);
    pack_w<<<dim3(64, 144), 256, 0, stream>>>(kw, vw, Wp);
    // H[4224][4608] = X[4224][2048] x Wp[4608][2048]^T
    gemm_bt<<<33 * 36, 256, 0, stream>>>(X, Wp, H, 4608, 2048, 1.f, 36);
    proj_rows<<<14848, 256, 0, stream>>>(H, kb, vb, gamma, beta, qks, qvs, sks, svs);
    transpose_svs<<<dim3(24, 36), 256, 0, stream>>>(svs, svsT);
    // scores[14080][768] = qks x sks^T / sqrt(1152)
    gemm_bt<<<110 * 6, 256, 0, stream>>>(qks, sks, scores, 768, 1152, 0.029462782549439484f, 6);
    softmax_attn<<<14080, 320, 0, stream>>>(scores, attn);
    proto_dist<<<110 * 9, 256, 0, stream>>>(attn, svsT, qvs, dist);
    finalize<<<10, 256, 0, stream>>>(dist, gt, tw, out);
}

// Round 2
// 501.334 us; speedup vs baseline: 1.4790x; 1.4790x over previous
//
#include <hip/hip_runtime.h>

typedef __bf16 bf16;
typedef __attribute__((ext_vector_type(8))) __bf16 bf16x8;
typedef __attribute__((ext_vector_type(4))) float f32x4;

#define AS1 __attribute__((address_space(1)))
#define AS3 __attribute__((address_space(3)))

// tuple tables: combinations(range(8), 2), lexicographic
__device__ __constant__ int c_T0[28] = {0,0,0,0,0,0,0,1,1,1,1,1,1,2,2,2,2,2,3,3,3,3,4,4,4,5,5,6};
__device__ __constant__ int c_T1[28] = {1,2,3,4,5,6,7,2,3,4,5,6,7,3,4,5,6,7,4,5,6,7,5,6,7,6,7,7};

// ---------------------------------------------------------------------------
// X = [frames 4224 x 2048] bf16, frame f: queries f<4000, support 4000..4199,
// pad rows >=4200 zero.  Adds positional encoding PE[s][d].
__global__ __launch_bounds__(256) void fill_x(
    const float* __restrict__ queries, const float* __restrict__ support,
    bf16* __restrict__ X)
{
    const int f = blockIdx.x, tid = threadIdx.x;
    bf16* row = X + (long)f * 2048;
    const int d0 = tid << 3;
    if (f >= 4200) {
        bf16x8 z;
        #pragma unroll
        for (int i = 0; i < 8; ++i) z[i] = (bf16)0.f;
        *(bf16x8*)(row + d0) = z;
        return;
    }
    const float* src = (f < 4000) ? (queries + (long)f * 2048)
                                  : (support + (long)(f - 4000) * 2048);
    const int s = f & 7;
    bf16x8 o;
    #pragma unroll
    for (int i = 0; i < 8; ++i) {
        int d = d0 + i;
        float dv = __expf((float)(d >> 1) * -0.008994473019508f); // -ln(1e4)/1024
        float ang = (float)s * dv;
        float pe = (d & 1) ? __cosf(ang) : __sinf(ang);
        o[i] = (bf16)(src[d] + pe);
    }
    *(bf16x8*)(row + d0) = o;
}

// ---------------------------------------------------------------------------
// Wp [4608][2048] bf16 = transposed halves: n<1152: k_w[0:2048], 1152..: k_w[2048:],
// 2304..: v_w[0:2048], 3456..: v_w[2048:]
__global__ __launch_bounds__(256) void pack_w(
    const float* __restrict__ kw, const float* __restrict__ vw, bf16* __restrict__ Wp)
{
    __shared__ float t[32][33];
    const int k0 = blockIdx.x << 5, n0g = blockIdx.y << 5;
    const int tx = threadIdx.x & 31, ty = threadIdx.x >> 5;
    const int j = n0g / 1152, nc = n0g % 1152;
    const float* src = ((j < 2) ? kw : vw) + (long)(((j & 1) << 11) + k0) * 1152 + nc;
    #pragma unroll
    for (int i = 0; i < 4; ++i)
        t[ty + (i << 3)][tx] = src[(long)(ty + (i << 3)) * 1152 + tx];
    __syncthreads();
    #pragma unroll
    for (int i = 0; i < 4; ++i)
        Wp[(long)(n0g + ty + (i << 3)) * 2048 + k0 + tx] = (bf16)t[tx][ty + (i << 3)];
}

// ---------------------------------------------------------------------------
// C[M,N] = scale * A[M,K](bf16,row-major) x B[N,K](bf16,row-major)^T
// M,N multiples of 128; K multiple of 32.  m97-style: 128x128 tile, 4 waves 2x2,
// global_load_lds width=16, 16x16x32 bf16 MFMA.  OutT in {float, bf16}.
template <typename OutT>
__global__ __launch_bounds__(256) void gemm_bt(
    const bf16* __restrict__ A, const bf16* __restrict__ B, OutT* __restrict__ C,
    int N, int K, float scale, int tiles_n)
{
    __shared__ __align__(16) bf16 lA[128 * 32];
    __shared__ __align__(16) bf16 lB[128 * 32];
    const int tid = threadIdx.x;
    const int wid = tid >> 6, lane = tid & 63;
    const int wm = (wid >> 1) << 6, wn = (wid & 1) << 6;
    const int quad = lane >> 4, l16 = lane & 15;
    const int tm = blockIdx.x / tiles_n, tn = blockIdx.x % tiles_n;
    const int m0 = tm << 7, n0 = tn << 7;

    f32x4 acc[4][4];
    #pragma unroll
    for (int i = 0; i < 4; ++i)
        #pragma unroll
        for (int j = 0; j < 4; ++j)
            #pragma unroll
            for (int r = 0; r < 4; ++r) acc[i][j][r] = 0.f;

    const int srow = lane >> 2, scol = (lane & 3) << 3;
    for (int kk = 0; kk < K; kk += 32) {
        __syncthreads();
        #pragma unroll
        for (int p = 0; p < 2; ++p) {
            const int rbase = (wid << 5) + (p << 4);
            const bf16* ga = A + (long)(m0 + rbase + srow) * K + kk + scol;
            const bf16* gb = B + (long)(n0 + rbase + srow) * K + kk + scol;
            __builtin_amdgcn_global_load_lds((const AS1 unsigned int*)ga,
                                             (AS3 unsigned int*)(lA + rbase * 32), 16, 0, 0);
            __builtin_amdgcn_global_load_lds((const AS1 unsigned int*)gb,
                                             (AS3 unsigned int*)(lB + rbase * 32), 16, 0, 0);
        }
        __builtin_amdgcn_s_waitcnt(0);
        __syncthreads();
        bf16x8 af[4], bfr[4];
        #pragma unroll
        for (int i = 0; i < 4; ++i)
            af[i] = *(const bf16x8*)(lA + (wm + (i << 4) + l16) * 32 + (quad << 3));
        #pragma unroll
        for (int j = 0; j < 4; ++j)
            bfr[j] = *(const bf16x8*)(lB + (wn + (j << 4) + l16) * 32 + (quad << 3));
        #pragma unroll
        for (int i = 0; i < 4; ++i)
            #pragma unroll
            for (int j = 0; j < 4; ++j)
                acc[i][j] = __builtin_amdgcn_mfma_f32_16x16x32_bf16(af[i], bfr[j], acc[i][j], 0, 0, 0);
    }
    #pragma unroll
    for (int i = 0; i < 4; ++i) {
        const int row = m0 + wm + (i << 4) + (quad << 2);
        #pragma unroll
        for (int j = 0; j < 4; ++j) {
            const int col = n0 + wn + (j << 4) + l16;
            OutT* cp = C + (long)row * N + col;
            #pragma unroll
            for (int r = 0; r < 4; ++r) cp[(long)r * N] = (OutT)(acc[i][j][r] * scale);
        }
    }
}

// ---------------------------------------------------------------------------
// One block per tuple-row: assemble K/V projections from half-projections H,
// LayerNorm on K, store bf16.  Also emits qv_sq[m] = ||q_vs row||^2 for query rows.
// H[f][0:1152]=k_top, [1152:2304]=k_bot, [2304:3456]=v_top, [3456:4608]=v_bot.
__global__ __launch_bounds__(256) void proj_rows(
    const float* __restrict__ H, const float* __restrict__ kb,
    const float* __restrict__ vb, const float* __restrict__ gamma,
    const float* __restrict__ beta,
    bf16* __restrict__ qks, bf16* __restrict__ qvs,
    bf16* __restrict__ sks, bf16* __restrict__ svs,
    float* __restrict__ qv_sq)
{
    const int bid = blockIdx.x, tid = threadIdx.x;
    bf16 *outK, *outV;
    int fi = 0, fj = 0;
    bool valid, isq = (bid < 14080);
    if (isq) {
        outK = qks + (long)bid * 1152;
        outV = qvs + (long)bid * 1152;
        valid = (bid < 14000);
        if (valid) {
            int q = bid / 28, t = bid - q * 28;
            fi = (q << 3) + c_T0[t];
            fj = (q << 3) + c_T1[t];
        }
    } else {
        int m2 = bid - 14080;
        outK = sks + (long)m2 * 1152;
        outV = svs + (long)m2 * 1152;
        valid = (m2 < 700);
        if (valid) {
            int n = m2 / 28, t = m2 - n * 28;
            fi = 4000 + (n << 3) + c_T0[t];
            fj = 4000 + (n << 3) + c_T1[t];
        }
    }
    if (!valid) {
        for (int d = tid; d < 1152; d += 256) { outK[d] = (bf16)0.f; outV[d] = (bf16)0.f; }
        if (isq && tid == 0) qv_sq[bid] = 0.f;
        return;
    }
    const float* Hi = H + (long)fi * 4608;
    const float* Hj = H + (long)fj * 4608;
    float xv[5];
    float sum = 0.f, sumsq = 0.f;
    #pragma unroll
    for (int it = 0; it < 5; ++it) {
        int d = tid + (it << 8);
        float x = 0.f;
        if (d < 1152) {
            x = Hi[d] + Hj[1152 + d] + kb[d];
            sum += x; sumsq += x * x;
        }
        xv[it] = x;
    }
    #pragma unroll
    for (int off = 32; off > 0; off >>= 1) {
        sum += __shfl_xor(sum, off, 64);
        sumsq += __shfl_xor(sumsq, off, 64);
    }
    __shared__ float s1[4], s2[4], s3[4];
    const int wid = tid >> 6;
    if ((tid & 63) == 0) { s1[wid] = sum; s2[wid] = sumsq; }
    __syncthreads();
    sum = s1[0] + s1[1] + s1[2] + s1[3];
    sumsq = s2[0] + s2[1] + s2[2] + s2[3];
    const float mu = sum * (1.f / 1152.f);
    const float var = sumsq * (1.f / 1152.f) - mu * mu;
    const float rs = rsqrtf(var + 1e-5f);
    #pragma unroll
    for (int it = 0; it < 5; ++it) {
        int d = tid + (it << 8);
        if (d < 1152) outK[d] = (bf16)((xv[it] - mu) * rs * gamma[d] + beta[d]);
    }
    float vsum = 0.f;
    #pragma unroll
    for (int it = 0; it < 5; ++it) {
        int d = tid + (it << 8);
        if (d < 1152) {
            bf16 bv = (bf16)(Hi[2304 + d] + Hj[3456 + d] + vb[d]);
            outV[d] = bv;
            float fv = (float)bv;
            vsum += fv * fv;
        }
    }
    if (isq) {
        #pragma unroll
        for (int off = 32; off > 0; off >>= 1) vsum += __shfl_xor(vsum, off, 64);
        if ((tid & 63) == 0) s3[wid] = vsum;
        __syncthreads();
        if (tid == 0) qv_sq[bid] = s3[0] + s3[1] + s3[2] + s3[3];
    }
}

// ---------------------------------------------------------------------------
// Gram mask: Gb[768][768] bf16 = block-diag(per-class 140x140) of Gf (f32).
__global__ __launch_bounds__(256) void mask_gram(
    const float* __restrict__ Gf, bf16* __restrict__ Gb)
{
    int i = blockIdx.x * 256 + threadIdx.x; // 2304 blocks
    int r = i / 768, col = i - r * 768;
    bool keep = (r < 700) && (col < 700) && (r / 140 == col / 140);
    Gb[i] = keep ? (bf16)Gf[i] : (bf16)0.f;
}

// ---------------------------------------------------------------------------
// Per query-tuple row: 5 independent softmaxes over 140 (one wave each).
// Also zeroes the tail cols 700..767 (read by the attnG GEMM).
__global__ __launch_bounds__(320) void softmax_attn(
    const float* __restrict__ scores, bf16* __restrict__ attn)
{
    const int m = blockIdx.x, tid = threadIdx.x;
    bf16* arow = attn + (long)m * 768;
    if (m >= 14000) {
        for (int d = tid; d < 768; d += 320) arow[d] = (bf16)0.f;
        return;
    }
    if (tid < 68) arow[700 + tid] = (bf16)0.f;
    const int w = tid >> 6, lane = tid & 63;
    const float* srow = scores + (long)m * 768 + w * 140;
    float v0 = srow[lane];
    float v1 = srow[64 + lane];
    float v2 = (lane < 12) ? srow[128 + lane] : -1e30f;
    float mx = fmaxf(fmaxf(v0, v1), v2);
    #pragma unroll
    for (int off = 32; off > 0; off >>= 1) mx = fmaxf(mx, __shfl_xor(mx, off, 64));
    float e0 = __expf(v0 - mx), e1 = __expf(v1 - mx);
    float e2 = (lane < 12) ? __expf(v2 - mx) : 0.f;
    float s = e0 + e1 + e2;
    #pragma unroll
    for (int off = 32; off > 0; off >>= 1) s += __shfl_xor(s, off, 64);
    const float inv = 1.f / s;
    bf16* aw = arow + w * 140;
    aw[lane] = (bf16)(e0 * inv);
    aw[64 + lane] = (bf16)(e1 * inv);
    if (lane < 12) aw[128 + lane] = (bf16)(e2 * inv);
}

// ---------------------------------------------------------------------------
// dist[c][q] += sum over tuple-rows m of  qv_sq[m] + sum_u a*(attnG - 2W).
// One wave per row m; grid = 14000/4.
__global__ __launch_bounds__(256) void final_dist(
    const bf16* __restrict__ attn, const bf16* __restrict__ attnG,
    const float* __restrict__ W, const float* __restrict__ qv_sq,
    float* __restrict__ dist)
{
    const int w = threadIdx.x >> 6, lane = threadIdx.x & 63;
    const int m = blockIdx.x * 4 + w; // < 14000
    const int q = m / 28;
    const bf16* ar = attn + (long)m * 768;
    const bf16* gr = attnG + (long)m * 768;
    const float* wr = W + (long)m * 768;
    const float qs = qv_sq[m];
    #pragma unroll
    for (int c = 0; c < 5; ++c) {
        const int base = c * 140;
        float s = 0.f;
        {
            int u = base + lane;
            float a = (float)ar[u];
            s += a * ((float)gr[u] - 2.f * wr[u]);
        }
        {
            int u = base + 64 + lane;
            float a = (float)ar[u];
            s += a * ((float)gr[u] - 2.f * wr[u]);
        }
        if (lane < 12) {
            int u = base + 128 + lane;
            float a = (float)ar[u];
            s += a * ((float)gr[u] - 2.f * wr[u]);
        }
        #pragma unroll
        for (int off = 32; off > 0; off >>= 1) s += __shfl_xor(s, off, 64);
        if (lane == 0) atomicAdd(&dist[c * 500 + q], s + qs);
    }
}

// ---------------------------------------------------------------------------
__global__ void finalize(const float* __restrict__ dist, const float* __restrict__ gt,
                         const float* __restrict__ tw, float* __restrict__ out)
{
    int i = blockIdx.x * 256 + threadIdx.x;
    if (i < 2500) {
        int q = i / 5, c = i - q * 5;
        out[i] = -dist[c * 500 + q] * (gt[0] * tw[0] * (1.f / 28.f));
    }
}

// ---------------------------------------------------------------------------
extern "C" void kernel_launch(void* const* d_in, const int* in_sizes, int n_in,
                              void* d_out, int out_size, void* d_ws, size_t ws_size,
                              hipStream_t stream)
{
    const float* support = (const float*)d_in[0];
    const float* queries = (const float*)d_in[2];
    const float* kw      = (const float*)d_in[3];
    const float* kb      = (const float*)d_in[4];
    const float* vw      = (const float*)d_in[5];
    const float* vb      = (const float*)d_in[6];
    const float* gamma   = (const float*)d_in[7];
    const float* beta    = (const float*)d_in[8];
    const float* gt      = (const float*)d_in[9];
    const float* tw      = (const float*)d_in[10];
    float* out = (float*)d_out;

    char* ws = (char*)d_ws;
    size_t off = 0;
    auto alloc = [&](size_t b) { char* p = ws + off; off += (b + 255) & ~(size_t)255; return p; };
    bf16* X     = (bf16*)alloc(4224ull * 2048 * 2);
    bf16* Wp    = (bf16*)alloc(4608ull * 2048 * 2);
    bf16* qks   = (bf16*)alloc(14080ull * 1152 * 2);
    bf16* qvs   = (bf16*)alloc(14080ull * 1152 * 2);
    bf16* sks   = (bf16*)alloc(768ull * 1152 * 2);
    bf16* svs   = (bf16*)alloc(768ull * 1152 * 2);
    bf16* attn  = (bf16*)alloc(14080ull * 768 * 2);
    float* Gf   = (float*)alloc(768ull * 768 * 4);
    bf16* Gb    = (bf16*)alloc(768ull * 768 * 2);
    float* qsq  = (float*)alloc(14080ull * 4);
    float* dist = (float*)alloc(5 * 500 * 4);
    float* H    = (float*)alloc(4224ull * 4608 * 4);
    // aliases into H (dead after proj_rows):
    float* scores = H;                                  // [14080 x 768] f32
    float* Wbuf   = H;                                  // [14080 x 768] f32 (after softmax)
    bf16*  attnG  = (bf16*)(H + 14080ull * 768);        // [14080 x 768] bf16

    hipMemsetAsync(dist, 0, 5 * 500 * 4, stream);
    fill_x<<<4224, 256, 0, stream>>>(queries, support, X);
    pack_w<<<dim3(64, 144), 256, 0, stream>>>(kw, vw, Wp);
    // H[4224][4608] = X x Wp^T
    gemm_bt<float><<<33 * 36, 256, 0, stream>>>(X, Wp, H, 4608, 2048, 1.f, 36);
    proj_rows<<<14848, 256, 0, stream>>>(H, kb, vb, gamma, beta, qks, qvs, sks, svs, qsq);
    // Gram: Gf[768][768] = svs x svs^T, then mask to block-diagonal bf16
    gemm_bt<float><<<6 * 6, 256, 0, stream>>>(svs, svs, Gf, 768, 1152, 1.f, 6);
    mask_gram<<<2304, 256, 0, stream>>>(Gf, Gb);
    // scores[14080][768] = qks x sks^T / sqrt(1152)
    gemm_bt<float><<<110 * 6, 256, 0, stream>>>(qks, sks, scores, 768, 1152, 0.029462782549439484f, 6);
    softmax_attn<<<14080, 320, 0, stream>>>(scores, attn);
    // W[14080][768] = qvs x svs^T   (overwrites scores region)
    gemm_bt<float><<<110 * 6, 256, 0, stream>>>(qvs, svs, Wbuf, 768, 1152, 1.f, 6);
    // attnG[14080][768] = attn x Gb^T (Gb symmetric per block)
    gemm_bt<bf16><<<110 * 6, 256, 0, stream>>>(attn, Gb, attnG, 768, 768, 1.f, 6);
    final_dist<<<3500, 256, 0, stream>>>(attn, attnG, Wbuf, qsq, dist);
    finalize<<<10, 256, 0, stream>>>(dist, gt, tw, out);
}